// Round 9
// baseline (228.454 us; speedup 1.0000x reference)
//
#include <hip/hip_runtime.h>
#include <hip/hip_bf16.h>
#include <stdint.h>

// Attention fwd: B=2, N=2048, D=768, H=12, Dh=64, INNER=768
// prep(x->bf16, w_qkv^T, w_out^T) -> [QKV gemm 128x96, 768 blocks=3/CU] ->
// [flash attn R9: R6-proven staged/1-barrier loop + kv-STRIP ownership:
//  wave w owns kv rows w*16..+15; S^T=K@Q^T so P stays in registers as PV
//  B-frags; per-wave O^T partials; epilogue ds_add_f32 on declared __shared__
//  float (R3's flat-atomic bug fixed). Loop LDS traffic 2.75x lower than R6
//  (no cross-wave B-frag broadcast redundancy, no P round-trip).] ->
// [out gemm 64x96, 512 blocks=2/CU]
// R8 post-mortem: Ps stride-68 broke ds_read_b128 16B alignment -> 73.7us.
// Conflicts 786K->0 was a red herring (1024 cyc/block = 2%).

typedef __attribute__((ext_vector_type(8))) short bf16x8;
typedef __attribute__((ext_vector_type(4))) short bf16x4;
typedef __attribute__((ext_vector_type(4))) float f32x4;
typedef __attribute__((address_space(3))) unsigned int lds_uint;
typedef __attribute__((address_space(1))) const unsigned int g_uint;

__device__ __forceinline__ short f2bf(float f) {
    union { float f; uint32_t u; } x; x.f = f;
    uint32_t r = (x.u + 0x7fffu + ((x.u >> 16) & 1u)) >> 16;
    return (short)r;
}
__device__ __forceinline__ uint32_t packbf(float a, float b) {
    union { float f; uint32_t u; } xa, xb; xa.f = a; xb.f = b;
    return __builtin_amdgcn_perm(xb.u + 0x8000u, xa.u + 0x8000u, 0x07060302u);
}
__device__ __forceinline__ float exp2fast(float x) {
#if __has_builtin(__builtin_amdgcn_exp2f)
    return __builtin_amdgcn_exp2f(x);
#else
    return __expf(x * 0.6931471805599453f);
#endif
}
__device__ __forceinline__ void gl_lds16(const void* g, void* l) {
    __builtin_amdgcn_global_load_lds((g_uint*)g, (lds_uint*)l, 16, 0, 0);
}

// ---------------------------------------------------------------------------
// 64x64 fp32->bf16 transpose tile (shared by prep_k / tr_w)
// ---------------------------------------------------------------------------
__device__ __forceinline__ void tr_tile(const float* __restrict__ W,
                                        short* __restrict__ Wt, int K, int N,
                                        int n0, int k0, int t, short* S) {
    {
        int kl = t >> 2, ng = t & 3;
        const float* src = W + (size_t)(k0 + kl) * N + n0 + ng * 16;
        #pragma unroll
        for (int j = 0; j < 16; j += 4) {
            float4 f = *(const float4*)(src + j);
            S[(ng*16 + j + 0) * 65 + kl] = f2bf(f.x);
            S[(ng*16 + j + 1) * 65 + kl] = f2bf(f.y);
            S[(ng*16 + j + 2) * 65 + kl] = f2bf(f.z);
            S[(ng*16 + j + 3) * 65 + kl] = f2bf(f.w);
        }
    }
    __syncthreads();
    {
        int nl = t >> 2, kg = t & 3;
        short* dst = Wt + (size_t)(n0 + nl) * K + k0 + kg * 16;
        #pragma unroll
        for (int j = 0; j < 16; j += 4) {
            short4 s4;
            s4.x = S[nl*65 + kg*16 + j + 0];
            s4.y = S[nl*65 + kg*16 + j + 1];
            s4.z = S[nl*65 + kg*16 + j + 2];
            s4.w = S[nl*65 + kg*16 + j + 3];
            *(short4*)(dst + j) = s4;
        }
    }
}

// fused prep: [0,1536) x->bf16 ; [1536,1968) w_qkv^T ; [1968,2112) w_out^T
__global__ __launch_bounds__(256)
void prep_k(const float* __restrict__ x, short* __restrict__ Xb,
            const float* __restrict__ Wq, short* __restrict__ Wqt,
            const float* __restrict__ Wo, short* __restrict__ Wot)
{
    __shared__ short S[64 * 65];
    const int t = threadIdx.x;
    if (blockIdx.x < 1536) {
        int i = (blockIdx.x * 256 + t) * 8;
        float4 f0 = *(const float4*)(x + i);
        float4 f1 = *(const float4*)(x + i + 4);
        short s[8];
        s[0]=f2bf(f0.x); s[1]=f2bf(f0.y); s[2]=f2bf(f0.z); s[3]=f2bf(f0.w);
        s[4]=f2bf(f1.x); s[5]=f2bf(f1.y); s[6]=f2bf(f1.z); s[7]=f2bf(f1.w);
        *(uint4*)(Xb + i) = *(uint4*)s;
        return;
    }
    if (blockIdx.x < 1968) {
        const int b2 = blockIdx.x - 1536;                  // N=2304, K=768
        tr_tile(Wq, Wqt, 768, 2304, (b2 % 36) * 64, (b2 / 36) * 64, t, S);
    } else {
        const int b3 = blockIdx.x - 1968;                  // N=768, K=768
        tr_tile(Wo, Wot, 768, 768, (b3 % 12) * 64, (b3 / 12) * 64, t, S);
    }
}

// standalone w_out transpose (fallback when Wot must alias Wqt)
__global__ __launch_bounds__(256)
void tr_w(const float* __restrict__ W, short* __restrict__ Wt, int K, int N) {
    __shared__ short S[64 * 65];
    tr_tile(W, Wt, K, N, blockIdx.x * 64, blockIdx.y * 64, threadIdx.x, S);
}

// ---------------------------------------------------------------------------
// QKV GEMM: 128x96 tiles, grid 24x32 = 768 blocks = 3/CU exact.
// [4096x768]bf16 @ Wqt[2304x768]^T + b -> Qb(pre-scaled)/Kb/Vt bf16
// Vt layout TILED: Vt[bh][kt][d][n&63] (64x64 tiles, 8KB, dense windows)
// ---------------------------------------------------------------------------
__global__ __launch_bounds__(256)
void gemm_qkv(const short* __restrict__ A, const short* __restrict__ Bt,
              const float* __restrict__ bias,
              short* __restrict__ Qb, short* __restrict__ Kb, short* __restrict__ Vt)
{
    __shared__ short As[128 * 32];     // 512 chunks of 16B
    __shared__ short Bs[96 * 32];      // 384 chunks
    const int tid = threadIdx.x, lane = tid & 63, w = tid >> 6;
    const int wm = w >> 1, wn = w & 1, quad = lane >> 4, lcol = lane & 15;
    const int bm = blockIdx.y * 128, bn = blockIdx.x * 96;

    f32x4 acc[4][3];
    #pragma unroll
    for (int i = 0; i < 4; i++)
        #pragma unroll
        for (int j = 0; j < 3; j++) acc[i][j] = (f32x4){0.f, 0.f, 0.f, 0.f};

    for (int kt = 0; kt < 768; kt += 32) {
        #pragma unroll
        for (int i = 0; i < 2; i++) {      // A: 512 chunks
            int c = tid + i * 256, row = c >> 2, cs = c & 3;
            gl_lds16(A + (size_t)(bm + row) * 768 + kt + cs * 8, As + c * 8);
        }
        {                                   // B: 384 chunks
            int c = tid, row = c >> 2, cs = c & 3;
            gl_lds16(Bt + (size_t)(bn + row) * 768 + kt + cs * 8, Bs + c * 8);
        }
        if (tid < 128) {
            int c = 256 + tid, row = c >> 2, cs = c & 3;
            gl_lds16(Bt + (size_t)(bn + row) * 768 + kt + cs * 8, Bs + c * 8);
        }
        __syncthreads();
        bf16x8 a[4], b[3];
        #pragma unroll
        for (int tm = 0; tm < 4; tm++)
            a[tm] = *(const bf16x8*)(As + (wm*64 + tm*16 + lcol) * 32 + quad * 8);
        #pragma unroll
        for (int tn = 0; tn < 3; tn++)
            b[tn] = *(const bf16x8*)(Bs + (wn*48 + tn*16 + lcol) * 32 + quad * 8);
        #pragma unroll
        for (int tm = 0; tm < 4; tm++)
            #pragma unroll
            for (int tn = 0; tn < 3; tn++)
                acc[tm][tn] = __builtin_amdgcn_mfma_f32_16x16x32_bf16(a[tm], b[tn], acc[tm][tn], 0, 0, 0);
        __syncthreads();
    }

    const float SCLQ = 0.18033688011112042f;   // 0.125 * log2(e) folded into Q
    #pragma unroll
    for (int tm = 0; tm < 4; tm++) {
        #pragma unroll
        for (int tn = 0; tn < 3; tn++) {
            int col = bn + wn*48 + tn*16 + lcol;
            float bv = bias[col];
            int which = (col >= 1536) ? 2 : (col >= 768 ? 1 : 0);
            int cc = col - which * 768;
            int h = cc >> 6, d = cc & 63;
            int rowbase = bm + wm*64 + tm*16 + quad*4;
            int bb = rowbase >> 11, n0 = rowbase & 2047;
            int bh = bb * 12 + h;
            if (which == 2) {                 // V: tiled V^T store, dense window
                short4 s4;
                s4.x = f2bf(acc[tm][tn][0] + bv);
                s4.y = f2bf(acc[tm][tn][1] + bv);
                s4.z = f2bf(acc[tm][tn][2] + bv);
                s4.w = f2bf(acc[tm][tn][3] + bv);
                *(short4*)(Vt + (((size_t)bh*32 + (n0 >> 6))*64 + d)*64 + (n0 & 63)) = s4;
            } else {
                #pragma unroll
                for (int reg = 0; reg < 4; reg++) {
                    float v = acc[tm][tn][reg] + bv;
                    if (which == 0) v *= SCLQ;
                    short* dst = (which == 0) ? Qb : Kb;
                    dst[((size_t)bh*2048 + n0 + reg)*64 + d] = f2bf(v);
                }
            }
        }
    }
}

// ---------------------------------------------------------------------------
// Flash attention R9. Block = (bh, 64-q tile), 256 thr, 768 blocks = 3/CU.
// R6-proven staged/double-buffered loop (1 barrier/tile, DMA prefetch), but
// wave w owns KV STRIP w*16..w*16+15:
//   S^T = K(strip)@Q^T : A = K a-frags (2x ds_read_b128, wave-private),
//                        B = Q frags preloaded global->reg once.
//   C-layout of S^T == B-frag layout of P^T -> P never leaves registers.
//   O^T(strip partial) += V^T(strip)@P^T via 16x16x16 (V: 4x ds_read_b64).
// Epilogue: O^T partials + l summed across waves via native ds_add_f32 on
// DECLARED __shared__ float (R3's generic-pointer flat-atomic bug avoided).
// ---------------------------------------------------------------------------
__global__ __launch_bounds__(256, 3)
void attn_k(const short* __restrict__ Q, const short* __restrict__ K,
            const short* __restrict__ Vt, short* __restrict__ Ab)
{
    __shared__ short Ks[2][4096];      // [kv][d] xor-swizzled chunks
    __shared__ short Vs[2][4096];      // [d][kv] xor-swizzled chunks
    __shared__ float Ored[64 * 66];    // [d][q] f32, stride 66 (2/bank = free)
    __shared__ float lsum[64];

    const int tid = threadIdx.x, lane = tid & 63, w = tid >> 6;
    const int quad = lane >> 4, lcol = lane & 15;
    const int bid = blockIdx.x;
    const int bh = bid % 24, qt = bid / 24;
    const int b = bh / 12, h = bh - b * 12;

    const short* Kg = K  + (size_t)bh * 131072;   // [n][d] rows, tile = 8KB
    const short* Vg = Vt + (size_t)bh * 131072;   // tiled [kt][d][n64], 8KB

    // Q as B-operand frags (q = qs*16+lcol, d = ks*32+quad*8), loaded once
    bf16x8 qf[4][2];
    {
        const short* Qg = Q + ((size_t)bh * 2048 + (size_t)qt * 64) * 64;
        #pragma unroll
        for (int qs = 0; qs < 4; qs++)
            #pragma unroll
            for (int ks = 0; ks < 2; ks++)
                qf[qs][ks] = *(const bf16x8*)(Qg + (qs*16 + lcol) * 64 + ks*32 + quad*8);
    }

    // zero the reduction scratch, stage tile 0
    #pragma unroll
    for (int i = 0; i < 17; i++) {
        int idx = tid + i * 256;
        if (idx < 64 * 66) Ored[idx] = 0.f;
    }
    if (tid < 64) lsum[tid] = 0.f;
    #pragma unroll
    for (int i = 0; i < 2; i++) {
        int c = tid + i * 256, row = c >> 3, cs = c & 7, gc = cs ^ (row & 7);
        gl_lds16(Kg + row * 64 + gc * 8, Ks[0] + c * 8);
        gl_lds16(Vg + row * 64 + gc * 8, Vs[0] + c * 8);
    }
    __syncthreads();

    f32x4 o[4][4];                     // o[ds][qs]: O^T[d=ds16+quad*4+r][q=qs16+lcol]
    #pragma unroll
    for (int i = 0; i < 4; i++)
        #pragma unroll
        for (int j = 0; j < 4; j++) o[i][j] = (f32x4){0.f, 0.f, 0.f, 0.f};
    float lp[4] = {0.f, 0.f, 0.f, 0.f};

    const int krow = w * 16 + lcol;            // this wave's K rows
    const int ksw  = krow & 7;                 // xor key for K chunk swizzle

    for (int kt = 0; kt < 32; kt++) {
        const int p = kt & 1;
        if (kt < 31) {                 // prefetch next K/V tile into other buffer
            #pragma unroll
            for (int i = 0; i < 2; i++) {
                int c = tid + i * 256, row = c >> 3, cs = c & 7, gc = cs ^ (row & 7);
                gl_lds16(Kg + (kt + 1) * 4096 + row * 64 + gc * 8, Ks[p ^ 1] + c * 8);
                gl_lds16(Vg + (kt + 1) * 4096 + row * 64 + gc * 8, Vs[p ^ 1] + c * 8);
            }
        }

        // S^T(strip) = K @ Q^T : lane gets P[q=qs*16+lcol][kv=w*16+quad*4+r]
        f32x4 st[4];
        #pragma unroll
        for (int qs = 0; qs < 4; qs++) st[qs] = (f32x4){0.f, 0.f, 0.f, 0.f};
        #pragma unroll
        for (int ks = 0; ks < 2; ks++) {
            bf16x8 kf = *(const bf16x8*)(Ks[p] + krow * 64 + (((ks*4 + quad) ^ ksw) << 3));
            #pragma unroll
            for (int qs = 0; qs < 4; qs++)
                st[qs] = __builtin_amdgcn_mfma_f32_16x16x32_bf16(kf, qf[qs][ks], st[qs], 0, 0, 0);
        }

        // V a-frags for this strip: V^T[d=ds*16+lcol][kv=w*16+quad*4..+3]
        bf16x4 vf[4];
        #pragma unroll
        for (int ds = 0; ds < 4; ds++) {
            int vrow = ds * 16 + lcol;
            vf[ds] = *(const bf16x4*)(Vs[p] + vrow * 64 +
                                      (((w*2 + (quad >> 1)) ^ (vrow & 7)) << 3) +
                                      (quad & 1) * 4);
        }

        // P = exp2(S^T) in registers -> PV B-frags; O^T += V^T @ P^T
        #pragma unroll
        for (int qs = 0; qs < 4; qs++) {
            float p0 = exp2fast(st[qs][0]), p1 = exp2fast(st[qs][1]);
            float p2 = exp2fast(st[qs][2]), p3 = exp2fast(st[qs][3]);
            lp[qs] += (p0 + p1) + (p2 + p3);
            uint32_t uu[2] = { packbf(p0, p1), packbf(p2, p3) };
            bf16x4 pf = *(bf16x4*)uu;
            #pragma unroll
            for (int ds = 0; ds < 4; ds++)
                o[ds][qs] = __builtin_amdgcn_mfma_f32_16x16x16bf16_1k(vf[ds], pf, o[ds][qs], 0, 0, 0);
        }
        __syncthreads();               // staging buffer swap (drains prefetch DMA)
    }

    // ---- epilogue: cross-wave reduction via native LDS atomics ----
    #pragma unroll
    for (int qs = 0; qs < 4; qs++) {
        float v = lp[qs];
        v += __shfl_xor(v, 16, 64);
        v += __shfl_xor(v, 32, 64);
        if (quad == 0) atomicAdd(&lsum[qs*16 + lcol], v);
    }
    #pragma unroll
    for (int ds = 0; ds < 4; ds++)
        #pragma unroll
        for (int qs = 0; qs < 4; qs++)
            #pragma unroll
            for (int r = 0; r < 4; r++)
                atomicAdd(&Ored[(ds*16 + quad*4 + r) * 66 + qs*16 + lcol], o[ds][qs][r]);
    __syncthreads();

    // write Ab[b, n=qt*64+q, h*64+d]; thread: q = tid>>2, d-chunk = (tid&3)*16
    {
        int q = tid >> 2, dg = (tid & 3) * 16;
        float rl = 1.0f / lsum[q];
        short sv[16];
        #pragma unroll
        for (int i = 0; i < 16; i++) sv[i] = f2bf(Ored[(dg + i) * 66 + q] * rl);
        short* dst = Ab + ((size_t)(b*2048 + qt*64 + q)) * 768 + h*64 + dg;
        *(uint4*)(dst)     = ((uint4*)sv)[0];
        *(uint4*)(dst + 8) = ((uint4*)sv)[1];
    }
}

// ---------------------------------------------------------------------------
// out-proj GEMM, 64x96 tiles (512 blocks = 2/CU exact): fp32 out + bias
// ---------------------------------------------------------------------------
__global__ __launch_bounds__(256)
void gemm_out(const short* __restrict__ A, const short* __restrict__ Bt,
              const float* __restrict__ bias, float* __restrict__ Of)
{
    __shared__ short As[64 * 32];      // 256 chunks
    __shared__ short Bs[96 * 32];      // 384 chunks
    const int tid = threadIdx.x, lane = tid & 63, w = tid >> 6;
    const int wm = w >> 1, wn = w & 1, quad = lane >> 4, lcol = lane & 15;
    const int bm = blockIdx.y * 64, bn = blockIdx.x * 96;

    f32x4 acc[2][3];
    #pragma unroll
    for (int i = 0; i < 2; i++)
        #pragma unroll
        for (int j = 0; j < 3; j++) acc[i][j] = (f32x4){0.f, 0.f, 0.f, 0.f};

    for (int kt = 0; kt < 768; kt += 32) {
        {
            int row = tid >> 2, cs = tid & 3;
            gl_lds16(A  + (size_t)(bm + row) * 768 + kt + cs * 8, As + tid * 8);
            gl_lds16(Bt + (size_t)(bn + row) * 768 + kt + cs * 8, Bs + tid * 8);
        }
        if (tid < 128) {
            int c = 256 + tid, row = c >> 2, cs = c & 3;
            gl_lds16(Bt + (size_t)(bn + row) * 768 + kt + cs * 8, Bs + c * 8);
        }
        __syncthreads();
        bf16x8 a[2], b[3];
        #pragma unroll
        for (int tm = 0; tm < 2; tm++)
            a[tm] = *(const bf16x8*)(As + (wm*32 + tm*16 + lcol) * 32 + quad * 8);
        #pragma unroll
        for (int tn = 0; tn < 3; tn++)
            b[tn] = *(const bf16x8*)(Bs + (wn*48 + tn*16 + lcol) * 32 + quad * 8);
        #pragma unroll
        for (int tm = 0; tm < 2; tm++)
            #pragma unroll
            for (int tn = 0; tn < 3; tn++)
                acc[tm][tn] = __builtin_amdgcn_mfma_f32_16x16x32_bf16(a[tm], b[tn], acc[tm][tn], 0, 0, 0);
        __syncthreads();
    }
    #pragma unroll
    for (int tm = 0; tm < 2; tm++) {
        #pragma unroll
        for (int tn = 0; tn < 3; tn++) {
            int col = bn + wn*48 + tn*16 + lcol;
            float bv = bias[col];
            #pragma unroll
            for (int reg = 0; reg < 4; reg++) {
                int row = bm + wm*32 + tm*16 + quad*4 + reg;
                Of[(size_t)row * 768 + col] = acc[tm][tn][reg] + bv;
            }
        }
    }
}

// ---------------------------------------------------------------------------
extern "C" void kernel_launch(void* const* d_in, const int* in_sizes, int n_in,
                              void* d_out, int out_size, void* d_ws, size_t ws_size,
                              hipStream_t stream)
{
    (void)in_sizes; (void)n_in; (void)out_size;
    const float* x     = (const float*)d_in[0];
    const float* w_qkv = (const float*)d_in[1];
    const float* b_qkv = (const float*)d_in[2];
    const float* w_out = (const float*)d_in[3];
    const float* b_out = (const float*)d_in[4];
    float* out = (float*)d_out;

    const size_t XSZ = (size_t)4096 * 768;
    const size_t WQ  = (size_t)2304 * 768;
    const size_t WO  = (size_t)768 * 768;
    const size_t HSZ = (size_t)24 * 2048 * 64;
    short* Xb  = (short*)d_ws;
    short* Wqt = Xb + XSZ;
    short* Qb  = Wqt + WQ;
    short* Kb  = Qb + HSZ;
    short* Vt  = Kb + HSZ;
    short* Ab  = Xb;                       // x dead after gemm_qkv

    const bool sepWot = ws_size >= (XSZ + WQ + 3*HSZ + WO) * sizeof(short);
    short* Wot = sepWot ? (Vt + HSZ) : Wqt;   // else alias (w_qkv^T dead after gemm0)

    if (sepWot) {
        prep_k<<<2112, 256, 0, stream>>>(x, Xb, w_qkv, Wqt, w_out, Wot);
        gemm_qkv<<<dim3(24, 32), 256, 0, stream>>>(Xb, Wqt, b_qkv, Qb, Kb, Vt);
    } else {
        prep_k<<<1968, 256, 0, stream>>>(x, Xb, w_qkv, Wqt, w_out, Wot);
        gemm_qkv<<<dim3(24, 32), 256, 0, stream>>>(Xb, Wqt, b_qkv, Qb, Kb, Vt);
        tr_w<<<dim3(12, 12), 256, 0, stream>>>(w_out, Wot, 768, 768);
    }
    attn_k<<<768, 256, 0, stream>>>(Qb, Kb, Vt, Ab);
    gemm_out<<<dim3(8, 64), 256, 0, stream>>>(Ab, Wot, b_out, out);
}

// Round 10
// 177.808 us; speedup vs baseline: 1.2848x; 1.2848x over previous
//
#include <hip/hip_runtime.h>
#include <hip/hip_bf16.h>
#include <stdint.h>

// Attention fwd: B=2, N=2048, D=768, H=12, Dh=64, INNER=768
// R10 = composition of best-measured components:
//   prep(x->bf16, w_qkv^T, w_out^T)
//   gemm_qkv 128x96 tiles, 768 blocks = 3/CU   (R8-measured)
//   attn_k   EXACT R6 kernel (57.5us proven): 256 thr, 768 blocks = 3/CU,
//            own-wave P strip stride-72, 1 barrier/tile, 16x16x32 MFMA only
//   gemm_out 64x96 tiles, 512 blocks = 2/CU    (R8-measured)
// Retired: register-P + mfma_16x16x16_1k family (R3/R4/R5/R9: 108-138us —
// _1k takes full MFMA issue slots at half FLOPs + VALU->MFMA operand serialization).
// R8's Ps stride-68 retired (broke ds_read_b128 16B alignment).

typedef __attribute__((ext_vector_type(8))) short bf16x8;
typedef __attribute__((ext_vector_type(4))) float f32x4;
typedef __attribute__((address_space(3))) unsigned int lds_uint;
typedef __attribute__((address_space(1))) const unsigned int g_uint;

__device__ __forceinline__ short f2bf(float f) {
    union { float f; uint32_t u; } x; x.f = f;
    uint32_t r = (x.u + 0x7fffu + ((x.u >> 16) & 1u)) >> 16;
    return (short)r;
}
__device__ __forceinline__ float exp2fast(float x) {
#if __has_builtin(__builtin_amdgcn_exp2f)
    return __builtin_amdgcn_exp2f(x);
#else
    return __expf(x * 0.6931471805599453f);
#endif
}
__device__ __forceinline__ void gl_lds16(const void* g, void* l) {
    __builtin_amdgcn_global_load_lds((g_uint*)g, (lds_uint*)l, 16, 0, 0);
}

// ---------------------------------------------------------------------------
// 64x64 fp32->bf16 transpose tile (shared by prep_k / tr_w)
// ---------------------------------------------------------------------------
__device__ __forceinline__ void tr_tile(const float* __restrict__ W,
                                        short* __restrict__ Wt, int K, int N,
                                        int n0, int k0, int t, short* S) {
    {
        int kl = t >> 2, ng = t & 3;
        const float* src = W + (size_t)(k0 + kl) * N + n0 + ng * 16;
        #pragma unroll
        for (int j = 0; j < 16; j += 4) {
            float4 f = *(const float4*)(src + j);
            S[(ng*16 + j + 0) * 65 + kl] = f2bf(f.x);
            S[(ng*16 + j + 1) * 65 + kl] = f2bf(f.y);
            S[(ng*16 + j + 2) * 65 + kl] = f2bf(f.z);
            S[(ng*16 + j + 3) * 65 + kl] = f2bf(f.w);
        }
    }
    __syncthreads();
    {
        int nl = t >> 2, kg = t & 3;
        short* dst = Wt + (size_t)(n0 + nl) * K + k0 + kg * 16;
        #pragma unroll
        for (int j = 0; j < 16; j += 4) {
            short4 s4;
            s4.x = S[nl*65 + kg*16 + j + 0];
            s4.y = S[nl*65 + kg*16 + j + 1];
            s4.z = S[nl*65 + kg*16 + j + 2];
            s4.w = S[nl*65 + kg*16 + j + 3];
            *(short4*)(dst + j) = s4;
        }
    }
}

// fused prep: [0,1536) x->bf16 ; [1536,1968) w_qkv^T ; [1968,2112) w_out^T
__global__ __launch_bounds__(256)
void prep_k(const float* __restrict__ x, short* __restrict__ Xb,
            const float* __restrict__ Wq, short* __restrict__ Wqt,
            const float* __restrict__ Wo, short* __restrict__ Wot)
{
    __shared__ short S[64 * 65];
    const int t = threadIdx.x;
    if (blockIdx.x < 1536) {
        int i = (blockIdx.x * 256 + t) * 8;
        float4 f0 = *(const float4*)(x + i);
        float4 f1 = *(const float4*)(x + i + 4);
        short s[8];
        s[0]=f2bf(f0.x); s[1]=f2bf(f0.y); s[2]=f2bf(f0.z); s[3]=f2bf(f0.w);
        s[4]=f2bf(f1.x); s[5]=f2bf(f1.y); s[6]=f2bf(f1.z); s[7]=f2bf(f1.w);
        *(uint4*)(Xb + i) = *(uint4*)s;
        return;
    }
    if (blockIdx.x < 1968) {
        const int b2 = blockIdx.x - 1536;                  // N=2304, K=768
        tr_tile(Wq, Wqt, 768, 2304, (b2 % 36) * 64, (b2 / 36) * 64, t, S);
    } else {
        const int b3 = blockIdx.x - 1968;                  // N=768, K=768
        tr_tile(Wo, Wot, 768, 768, (b3 % 12) * 64, (b3 / 12) * 64, t, S);
    }
}

// standalone w_out transpose (fallback when Wot must alias Wqt)
__global__ __launch_bounds__(256)
void tr_w(const float* __restrict__ W, short* __restrict__ Wt, int K, int N) {
    __shared__ short S[64 * 65];
    tr_tile(W, Wt, K, N, blockIdx.x * 64, blockIdx.y * 64, threadIdx.x, S);
}

// ---------------------------------------------------------------------------
// QKV GEMM: 128x96 tiles, grid 24x32 = 768 blocks = 3/CU exact.
// [4096x768]bf16 @ Wqt[2304x768]^T + b -> Qb(pre-scaled)/Kb/Vt bf16
// Vt layout TILED: Vt[bh][kt][d][n&63] (64x64 tiles, 8KB, dense windows)
// ---------------------------------------------------------------------------
__global__ __launch_bounds__(256)
void gemm_qkv(const short* __restrict__ A, const short* __restrict__ Bt,
              const float* __restrict__ bias,
              short* __restrict__ Qb, short* __restrict__ Kb, short* __restrict__ Vt)
{
    __shared__ short As[128 * 32];     // 512 chunks of 16B
    __shared__ short Bs[96 * 32];      // 384 chunks
    const int tid = threadIdx.x, lane = tid & 63, w = tid >> 6;
    const int wm = w >> 1, wn = w & 1, quad = lane >> 4, lcol = lane & 15;
    const int bm = blockIdx.y * 128, bn = blockIdx.x * 96;

    f32x4 acc[4][3];
    #pragma unroll
    for (int i = 0; i < 4; i++)
        #pragma unroll
        for (int j = 0; j < 3; j++) acc[i][j] = (f32x4){0.f, 0.f, 0.f, 0.f};

    for (int kt = 0; kt < 768; kt += 32) {
        #pragma unroll
        for (int i = 0; i < 2; i++) {      // A: 512 chunks
            int c = tid + i * 256, row = c >> 2, cs = c & 3;
            gl_lds16(A + (size_t)(bm + row) * 768 + kt + cs * 8, As + c * 8);
        }
        {                                   // B: 384 chunks
            int c = tid, row = c >> 2, cs = c & 3;
            gl_lds16(Bt + (size_t)(bn + row) * 768 + kt + cs * 8, Bs + c * 8);
        }
        if (tid < 128) {
            int c = 256 + tid, row = c >> 2, cs = c & 3;
            gl_lds16(Bt + (size_t)(bn + row) * 768 + kt + cs * 8, Bs + c * 8);
        }
        __syncthreads();
        bf16x8 a[4], b[3];
        #pragma unroll
        for (int tm = 0; tm < 4; tm++)
            a[tm] = *(const bf16x8*)(As + (wm*64 + tm*16 + lcol) * 32 + quad * 8);
        #pragma unroll
        for (int tn = 0; tn < 3; tn++)
            b[tn] = *(const bf16x8*)(Bs + (wn*48 + tn*16 + lcol) * 32 + quad * 8);
        #pragma unroll
        for (int tm = 0; tm < 4; tm++)
            #pragma unroll
            for (int tn = 0; tn < 3; tn++)
                acc[tm][tn] = __builtin_amdgcn_mfma_f32_16x16x32_bf16(a[tm], b[tn], acc[tm][tn], 0, 0, 0);
        __syncthreads();
    }

    const float SCLQ = 0.18033688011112042f;   // 0.125 * log2(e) folded into Q
    #pragma unroll
    for (int tm = 0; tm < 4; tm++) {
        #pragma unroll
        for (int tn = 0; tn < 3; tn++) {
            int col = bn + wn*48 + tn*16 + lcol;
            float bv = bias[col];
            int which = (col >= 1536) ? 2 : (col >= 768 ? 1 : 0);
            int cc = col - which * 768;
            int h = cc >> 6, d = cc & 63;
            int rowbase = bm + wm*64 + tm*16 + quad*4;
            int bb = rowbase >> 11, n0 = rowbase & 2047;
            int bh = bb * 12 + h;
            if (which == 2) {                 // V: tiled V^T store, dense window
                short4 s4;
                s4.x = f2bf(acc[tm][tn][0] + bv);
                s4.y = f2bf(acc[tm][tn][1] + bv);
                s4.z = f2bf(acc[tm][tn][2] + bv);
                s4.w = f2bf(acc[tm][tn][3] + bv);
                *(short4*)(Vt + (((size_t)bh*32 + (n0 >> 6))*64 + d)*64 + (n0 & 63)) = s4;
            } else {
                #pragma unroll
                for (int reg = 0; reg < 4; reg++) {
                    float v = acc[tm][tn][reg] + bv;
                    if (which == 0) v *= SCLQ;
                    short* dst = (which == 0) ? Qb : Kb;
                    dst[((size_t)bh*2048 + n0 + reg)*64 + d] = f2bf(v);
                }
            }
        }
    }
}

// ---------------------------------------------------------------------------
// Flash attention — EXACT R6 kernel (57.5us measured). Block = (bh, 64-q
// tile), 256 thr / 4 waves, 768 blocks = 3/CU. Wave w owns q-rows w*16..+15
// end to end; P round-trips through wave-PRIVATE LDS strip stride 72
// (same-wave RAW -> lgkmcnt only, no barrier; 16B-aligned b128 reads).
// 1 barrier/tile. No-max softmax (pre-scaled Q, exp2 safe).
// ---------------------------------------------------------------------------
__global__ __launch_bounds__(256)
void attn_k(const short* __restrict__ Q, const short* __restrict__ K,
            const short* __restrict__ Vt, short* __restrict__ Ab)
{
    __shared__ short Ks[2][4096];      // [kv][d] xor-swizzled chunks
    __shared__ short Vs[2][4096];      // [d][kv] xor-swizzled chunks
    __shared__ short Ps[4][16 * 72];   // per-wave P strip [q16][kv64], pad 72

    const int tid = threadIdx.x, lane = tid & 63, w = tid >> 6;
    const int quad = lane >> 4, lcol = lane & 15;
    const int bid = blockIdx.x;
    const int bh = bid % 24, qt = bid / 24;
    const int b = bh / 12, h = bh - b * 12;

    const short* Kg = K  + (size_t)bh * 131072;   // [n][d] rows, tile = 8KB
    const short* Vg = Vt + (size_t)bh * 131072;   // tiled [kt][d][n64], 8KB

    // Q a-frags direct global->reg (wave-private rows, iteration-invariant)
    bf16x8 qf[2];
    {
        const short* Qg = Q + ((size_t)bh * 2048 + (size_t)qt * 64 + w * 16 + lcol) * 64;
        qf[0] = *(const bf16x8*)(Qg + quad * 8);
        qf[1] = *(const bf16x8*)(Qg + 32 + quad * 8);
    }

    // stage tile 0: K + V (512 chunks each, 2 chunks/thread each)
    #pragma unroll
    for (int i = 0; i < 2; i++) {
        int c = tid + i * 256, row = c >> 3, cs = c & 7, gc = cs ^ (row & 7);
        gl_lds16(Kg + row * 64 + gc * 8, Ks[0] + c * 8);
        gl_lds16(Vg + row * 64 + gc * 8, Vs[0] + c * 8);
    }
    __syncthreads();

    f32x4 o[4];                        // o[tn][r] = O[q=w16+quad*4+r][d=tn*16+lcol]
    #pragma unroll
    for (int tn = 0; tn < 4; tn++) o[tn] = (f32x4){0.f, 0.f, 0.f, 0.f};
    float lp[4] = {0.f, 0.f, 0.f, 0.f};

    short* Pw = Ps[w];

    for (int kt = 0; kt < 32; kt++) {
        const int p = kt & 1;
        if (kt < 31) {                 // prefetch next K/V tile into other buffer
            #pragma unroll
            for (int i = 0; i < 2; i++) {
                int c = tid + i * 256, row = c >> 3, cs = c & 7, gc = cs ^ (row & 7);
                gl_lds16(Kg + (kt + 1) * 4096 + row * 64 + gc * 8, Ks[p ^ 1] + c * 8);
                gl_lds16(Vg + (kt + 1) * 4096 + row * 64 + gc * 8, Vs[p ^ 1] + c * 8);
            }
        }

        // S[q16][kv64]: A = Q (regs), B = K rows (4 tn strips x 2 ks)
        f32x4 st[4];
        #pragma unroll
        for (int tn = 0; tn < 4; tn++) st[tn] = (f32x4){0.f, 0.f, 0.f, 0.f};
        #pragma unroll
        for (int ks = 0; ks < 2; ks++) {
            #pragma unroll
            for (int tn = 0; tn < 4; tn++) {
                int row = tn * 16 + lcol;
                bf16x8 bk = *(const bf16x8*)(Ks[p] + row * 64 +
                                             (((ks * 4 + quad) ^ (row & 7)) << 3));
                st[tn] = __builtin_amdgcn_mfma_f32_16x16x32_bf16(qf[ks], bk, st[tn], 0, 0, 0);
            }
        }

        // P = exp2(S); own-strip LDS write (no barrier needed: same-wave RAW)
        #pragma unroll
        for (int tn = 0; tn < 4; tn++) {
            #pragma unroll
            for (int r = 0; r < 4; r++) {
                float pv = exp2fast(st[tn][r]);
                lp[r] += pv;
                union { float f; uint32_t u; } c; c.f = pv;
                Pw[(quad*4 + r) * 72 + tn*16 + lcol] = (short)((c.u + 0x8000u) >> 16);
            }
        }

        // O += P @ V : A = own P strip, B = V^T rows
        #pragma unroll
        for (int ks = 0; ks < 2; ks++) {
            bf16x8 ap = *(const bf16x8*)(Pw + lcol * 72 + ks * 32 + quad * 8);
            #pragma unroll
            for (int tn = 0; tn < 4; tn++) {
                int row = tn * 16 + lcol;
                bf16x8 bv = *(const bf16x8*)(Vs[p] + row * 64 +
                                             (((ks * 4 + quad) ^ (row & 7)) << 3));
                o[tn] = __builtin_amdgcn_mfma_f32_16x16x32_bf16(ap, bv, o[tn], 0, 0, 0);
            }
        }
        __syncthreads();               // staging buffer swap (drains prefetch DMA)
    }

    // epilogue: l[q] over 16 lcol lanes, normalize, write
    float rl[4];
    #pragma unroll
    for (int r = 0; r < 4; r++) {
        float v = lp[r];
        v += __shfl_xor(v, 1, 16);
        v += __shfl_xor(v, 2, 16);
        v += __shfl_xor(v, 4, 16);
        v += __shfl_xor(v, 8, 16);
        rl[r] = 1.0f / v;
    }
    #pragma unroll
    for (int tn = 0; tn < 4; tn++) {
        #pragma unroll
        for (int r = 0; r < 4; r++) {
            int q = qt * 64 + w * 16 + quad * 4 + r;
            int d = h * 64 + tn * 16 + lcol;
            Ab[((size_t)(b * 2048 + q)) * 768 + d] = f2bf(o[tn][r] * rl[r]);
        }
    }
}

// ---------------------------------------------------------------------------
// out-proj GEMM, 64x96 tiles (512 blocks = 2/CU exact): fp32 out + bias
// ---------------------------------------------------------------------------
__global__ __launch_bounds__(256)
void gemm_out(const short* __restrict__ A, const short* __restrict__ Bt,
              const float* __restrict__ bias, float* __restrict__ Of)
{
    __shared__ short As[64 * 32];      // 256 chunks
    __shared__ short Bs[96 * 32];      // 384 chunks
    const int tid = threadIdx.x, lane = tid & 63, w = tid >> 6;
    const int wm = w >> 1, wn = w & 1, quad = lane >> 4, lcol = lane & 15;
    const int bm = blockIdx.y * 64, bn = blockIdx.x * 96;

    f32x4 acc[2][3];
    #pragma unroll
    for (int i = 0; i < 2; i++)
        #pragma unroll
        for (int j = 0; j < 3; j++) acc[i][j] = (f32x4){0.f, 0.f, 0.f, 0.f};

    for (int kt = 0; kt < 768; kt += 32) {
        {
            int row = tid >> 2, cs = tid & 3;
            gl_lds16(A  + (size_t)(bm + row) * 768 + kt + cs * 8, As + tid * 8);
            gl_lds16(Bt + (size_t)(bn + row) * 768 + kt + cs * 8, Bs + tid * 8);
        }
        if (tid < 128) {
            int c = 256 + tid, row = c >> 2, cs = c & 3;
            gl_lds16(Bt + (size_t)(bn + row) * 768 + kt + cs * 8, Bs + c * 8);
        }
        __syncthreads();
        bf16x8 a[2], b[3];
        #pragma unroll
        for (int tm = 0; tm < 2; tm++)
            a[tm] = *(const bf16x8*)(As + (wm*32 + tm*16 + lcol) * 32 + quad * 8);
        #pragma unroll
        for (int tn = 0; tn < 3; tn++)
            b[tn] = *(const bf16x8*)(Bs + (wn*48 + tn*16 + lcol) * 32 + quad * 8);
        #pragma unroll
        for (int tm = 0; tm < 2; tm++)
            #pragma unroll
            for (int tn = 0; tn < 3; tn++)
                acc[tm][tn] = __builtin_amdgcn_mfma_f32_16x16x32_bf16(a[tm], b[tn], acc[tm][tn], 0, 0, 0);
        __syncthreads();
    }
    #pragma unroll
    for (int tm = 0; tm < 2; tm++) {
        #pragma unroll
        for (int tn = 0; tn < 3; tn++) {
            int col = bn + wn*48 + tn*16 + lcol;
            float bv = bias[col];
            #pragma unroll
            for (int reg = 0; reg < 4; reg++) {
                int row = bm + wm*32 + tm*16 + quad*4 + reg;
                Of[(size_t)row * 768 + col] = acc[tm][tn][reg] + bv;
            }
        }
    }
}

// ---------------------------------------------------------------------------
extern "C" void kernel_launch(void* const* d_in, const int* in_sizes, int n_in,
                              void* d_out, int out_size, void* d_ws, size_t ws_size,
                              hipStream_t stream)
{
    (void)in_sizes; (void)n_in; (void)out_size;
    const float* x     = (const float*)d_in[0];
    const float* w_qkv = (const float*)d_in[1];
    const float* b_qkv = (const float*)d_in[2];
    const float* w_out = (const float*)d_in[3];
    const float* b_out = (const float*)d_in[4];
    float* out = (float*)d_out;

    const size_t XSZ = (size_t)4096 * 768;
    const size_t WQ  = (size_t)2304 * 768;
    const size_t WO  = (size_t)768 * 768;
    const size_t HSZ = (size_t)24 * 2048 * 64;
    short* Xb  = (short*)d_ws;
    short* Wqt = Xb + XSZ;
    short* Qb  = Wqt + WQ;
    short* Kb  = Qb + HSZ;
    short* Vt  = Kb + HSZ;
    short* Ab  = Xb;                       // x dead after gemm_qkv

    const bool sepWot = ws_size >= (XSZ + WQ + 3*HSZ + WO) * sizeof(short);
    short* Wot = sepWot ? (Vt + HSZ) : Wqt;   // else alias (w_qkv^T dead after gemm0)

    if (sepWot) {
        prep_k<<<2112, 256, 0, stream>>>(x, Xb, w_qkv, Wqt, w_out, Wot);
        gemm_qkv<<<dim3(24, 32), 256, 0, stream>>>(Xb, Wqt, b_qkv, Qb, Kb, Vt);
    } else {
        prep_k<<<1968, 256, 0, stream>>>(x, Xb, w_qkv, Wqt, w_out, Wot);
        gemm_qkv<<<dim3(24, 32), 256, 0, stream>>>(Xb, Wqt, b_qkv, Qb, Kb, Vt);
        tr_w<<<dim3(12, 12), 256, 0, stream>>>(w_out, Wot, 768, 768);
    }
    attn_k<<<768, 256, 0, stream>>>(Qb, Kb, Vt, Ab);
    gemm_out<<<dim3(8, 64), 256, 0, stream>>>(Ab, Wot, b_out, out);
}

// Round 11
// 175.058 us; speedup vs baseline: 1.3050x; 1.0157x over previous
//
#include <hip/hip_runtime.h>
#include <hip/hip_bf16.h>
#include <stdint.h>

// Attention fwd: B=2, N=2048, D=768, H=12, Dh=64, INNER=768
// R11 = R10 with ONE change: attn S-phase flipped to S^T = K(strip,A) @ Q(all,B-regs).
//   - K reads: 8 -> 2 ds_read_b128 per wave-tile (kills 4-way cross-wave broadcast)
//   - S^T C-layout gives 4 consecutive kv per lane -> P-writes 16xb16 -> 4xb64
//   - P now a shared [64][72] tile -> 2 barriers/tile (visibility + staging swap)
//   - PV phase + epilogue unchanged from R6 (bench-verified); l via cross-wave ds_add
// All other kernels byte-identical to R10 (attn dur is separately observable).

typedef __attribute__((ext_vector_type(8))) short bf16x8;
typedef __attribute__((ext_vector_type(4))) float f32x4;
typedef __attribute__((address_space(3))) unsigned int lds_uint;
typedef __attribute__((address_space(1))) const unsigned int g_uint;

__device__ __forceinline__ short f2bf(float f) {
    union { float f; uint32_t u; } x; x.f = f;
    uint32_t r = (x.u + 0x7fffu + ((x.u >> 16) & 1u)) >> 16;
    return (short)r;
}
__device__ __forceinline__ uint32_t packbf(float a, float b) {
    union { float f; uint32_t u; } xa, xb; xa.f = a; xb.f = b;
    return __builtin_amdgcn_perm(xb.u + 0x8000u, xa.u + 0x8000u, 0x07060302u);
}
__device__ __forceinline__ float exp2fast(float x) {
#if __has_builtin(__builtin_amdgcn_exp2f)
    return __builtin_amdgcn_exp2f(x);
#else
    return __expf(x * 0.6931471805599453f);
#endif
}
__device__ __forceinline__ void gl_lds16(const void* g, void* l) {
    __builtin_amdgcn_global_load_lds((g_uint*)g, (lds_uint*)l, 16, 0, 0);
}

// ---------------------------------------------------------------------------
// 64x64 fp32->bf16 transpose tile (shared by prep_k / tr_w)
// ---------------------------------------------------------------------------
__device__ __forceinline__ void tr_tile(const float* __restrict__ W,
                                        short* __restrict__ Wt, int K, int N,
                                        int n0, int k0, int t, short* S) {
    {
        int kl = t >> 2, ng = t & 3;
        const float* src = W + (size_t)(k0 + kl) * N + n0 + ng * 16;
        #pragma unroll
        for (int j = 0; j < 16; j += 4) {
            float4 f = *(const float4*)(src + j);
            S[(ng*16 + j + 0) * 65 + kl] = f2bf(f.x);
            S[(ng*16 + j + 1) * 65 + kl] = f2bf(f.y);
            S[(ng*16 + j + 2) * 65 + kl] = f2bf(f.z);
            S[(ng*16 + j + 3) * 65 + kl] = f2bf(f.w);
        }
    }
    __syncthreads();
    {
        int nl = t >> 2, kg = t & 3;
        short* dst = Wt + (size_t)(n0 + nl) * K + k0 + kg * 16;
        #pragma unroll
        for (int j = 0; j < 16; j += 4) {
            short4 s4;
            s4.x = S[nl*65 + kg*16 + j + 0];
            s4.y = S[nl*65 + kg*16 + j + 1];
            s4.z = S[nl*65 + kg*16 + j + 2];
            s4.w = S[nl*65 + kg*16 + j + 3];
            *(short4*)(dst + j) = s4;
        }
    }
}

// fused prep: [0,1536) x->bf16 ; [1536,1968) w_qkv^T ; [1968,2112) w_out^T
__global__ __launch_bounds__(256)
void prep_k(const float* __restrict__ x, short* __restrict__ Xb,
            const float* __restrict__ Wq, short* __restrict__ Wqt,
            const float* __restrict__ Wo, short* __restrict__ Wot)
{
    __shared__ short S[64 * 65];
    const int t = threadIdx.x;
    if (blockIdx.x < 1536) {
        int i = (blockIdx.x * 256 + t) * 8;
        float4 f0 = *(const float4*)(x + i);
        float4 f1 = *(const float4*)(x + i + 4);
        short s[8];
        s[0]=f2bf(f0.x); s[1]=f2bf(f0.y); s[2]=f2bf(f0.z); s[3]=f2bf(f0.w);
        s[4]=f2bf(f1.x); s[5]=f2bf(f1.y); s[6]=f2bf(f1.z); s[7]=f2bf(f1.w);
        *(uint4*)(Xb + i) = *(uint4*)s;
        return;
    }
    if (blockIdx.x < 1968) {
        const int b2 = blockIdx.x - 1536;                  // N=2304, K=768
        tr_tile(Wq, Wqt, 768, 2304, (b2 % 36) * 64, (b2 / 36) * 64, t, S);
    } else {
        const int b3 = blockIdx.x - 1968;                  // N=768, K=768
        tr_tile(Wo, Wot, 768, 768, (b3 % 12) * 64, (b3 / 12) * 64, t, S);
    }
}

// standalone w_out transpose (fallback when Wot must alias Wqt)
__global__ __launch_bounds__(256)
void tr_w(const float* __restrict__ W, short* __restrict__ Wt, int K, int N) {
    __shared__ short S[64 * 65];
    tr_tile(W, Wt, K, N, blockIdx.x * 64, blockIdx.y * 64, threadIdx.x, S);
}

// ---------------------------------------------------------------------------
// QKV GEMM: 128x96 tiles, grid 24x32 = 768 blocks = 3/CU exact.
// [4096x768]bf16 @ Wqt[2304x768]^T + b -> Qb(pre-scaled)/Kb/Vt bf16
// Vt layout TILED: Vt[bh][kt][d][n&63] (64x64 tiles, 8KB, dense windows)
// ---------------------------------------------------------------------------
__global__ __launch_bounds__(256)
void gemm_qkv(const short* __restrict__ A, const short* __restrict__ Bt,
              const float* __restrict__ bias,
              short* __restrict__ Qb, short* __restrict__ Kb, short* __restrict__ Vt)
{
    __shared__ short As[128 * 32];     // 512 chunks of 16B
    __shared__ short Bs[96 * 32];      // 384 chunks
    const int tid = threadIdx.x, lane = tid & 63, w = tid >> 6;
    const int wm = w >> 1, wn = w & 1, quad = lane >> 4, lcol = lane & 15;
    const int bm = blockIdx.y * 128, bn = blockIdx.x * 96;

    f32x4 acc[4][3];
    #pragma unroll
    for (int i = 0; i < 4; i++)
        #pragma unroll
        for (int j = 0; j < 3; j++) acc[i][j] = (f32x4){0.f, 0.f, 0.f, 0.f};

    for (int kt = 0; kt < 768; kt += 32) {
        #pragma unroll
        for (int i = 0; i < 2; i++) {      // A: 512 chunks
            int c = tid + i * 256, row = c >> 2, cs = c & 3;
            gl_lds16(A + (size_t)(bm + row) * 768 + kt + cs * 8, As + c * 8);
        }
        {                                   // B: 384 chunks
            int c = tid, row = c >> 2, cs = c & 3;
            gl_lds16(Bt + (size_t)(bn + row) * 768 + kt + cs * 8, Bs + c * 8);
        }
        if (tid < 128) {
            int c = 256 + tid, row = c >> 2, cs = c & 3;
            gl_lds16(Bt + (size_t)(bn + row) * 768 + kt + cs * 8, Bs + c * 8);
        }
        __syncthreads();
        bf16x8 a[4], b[3];
        #pragma unroll
        for (int tm = 0; tm < 4; tm++)
            a[tm] = *(const bf16x8*)(As + (wm*64 + tm*16 + lcol) * 32 + quad * 8);
        #pragma unroll
        for (int tn = 0; tn < 3; tn++)
            b[tn] = *(const bf16x8*)(Bs + (wn*48 + tn*16 + lcol) * 32 + quad * 8);
        #pragma unroll
        for (int tm = 0; tm < 4; tm++)
            #pragma unroll
            for (int tn = 0; tn < 3; tn++)
                acc[tm][tn] = __builtin_amdgcn_mfma_f32_16x16x32_bf16(a[tm], b[tn], acc[tm][tn], 0, 0, 0);
        __syncthreads();
    }

    const float SCLQ = 0.18033688011112042f;   // 0.125 * log2(e) folded into Q
    #pragma unroll
    for (int tm = 0; tm < 4; tm++) {
        #pragma unroll
        for (int tn = 0; tn < 3; tn++) {
            int col = bn + wn*48 + tn*16 + lcol;
            float bv = bias[col];
            int which = (col >= 1536) ? 2 : (col >= 768 ? 1 : 0);
            int cc = col - which * 768;
            int h = cc >> 6, d = cc & 63;
            int rowbase = bm + wm*64 + tm*16 + quad*4;
            int bb = rowbase >> 11, n0 = rowbase & 2047;
            int bh = bb * 12 + h;
            if (which == 2) {                 // V: tiled V^T store, dense window
                short4 s4;
                s4.x = f2bf(acc[tm][tn][0] + bv);
                s4.y = f2bf(acc[tm][tn][1] + bv);
                s4.z = f2bf(acc[tm][tn][2] + bv);
                s4.w = f2bf(acc[tm][tn][3] + bv);
                *(short4*)(Vt + (((size_t)bh*32 + (n0 >> 6))*64 + d)*64 + (n0 & 63)) = s4;
            } else {
                #pragma unroll
                for (int reg = 0; reg < 4; reg++) {
                    float v = acc[tm][tn][reg] + bv;
                    if (which == 0) v *= SCLQ;
                    short* dst = (which == 0) ? Qb : Kb;
                    dst[((size_t)bh*2048 + n0 + reg)*64 + d] = f2bf(v);
                }
            }
        }
    }
}

// ---------------------------------------------------------------------------
// Flash attention R11. Block = (bh, 64-q tile), 256 thr, 768 blocks = 3/CU.
// S^T phase: A = K strip (wave-private rows w*16..+15, 2 ds_read_b128),
//            B = Q frags for ALL 64 q, preloaded to registers (32 VGPR).
//   Lane gets P[q=qs*16+lcol][kv=w*16+quad*4+r] (mapping bench-verified in R9)
//   -> 4 consecutive kv/lane -> P-write = 4 ds_write_b64 into shared Ps[64][72].
// barrier#1 (P visibility; also drains loop-top DMA prefetch).
// PV phase: unchanged R6 (wave w owns q-strip w; A = Ps rows, B = V rows).
// barrier#2 (staging swap + Ps reuse). l: register partials -> cross-wave
// ds atomicAdd at end (declared __shared__ float -> native ds_add).
// ---------------------------------------------------------------------------
__global__ __launch_bounds__(256)
void attn_k(const short* __restrict__ Q, const short* __restrict__ K,
            const short* __restrict__ Vt, short* __restrict__ Ab)
{
    __shared__ short Ks[2][4096];      // [kv][d] xor-swizzled chunks
    __shared__ short Vs[2][4096];      // [d][kv] xor-swizzled chunks
    __shared__ short Ps[64 * 72];      // shared P tile [q][kv], pad 72
    __shared__ float lsum[64];

    const int tid = threadIdx.x, lane = tid & 63, w = tid >> 6;
    const int quad = lane >> 4, lcol = lane & 15;
    const int bid = blockIdx.x;
    const int bh = bid % 24, qt = bid / 24;
    const int b = bh / 12, h = bh - b * 12;

    const short* Kg = K  + (size_t)bh * 131072;   // [n][d] rows, tile = 8KB
    const short* Vg = Vt + (size_t)bh * 131072;   // tiled [kt][d][n64], 8KB

    // Q as B-operand frags for ALL 64 q (q = qs*16+lcol, d = ks*32+quad*8)
    bf16x8 qf[4][2];
    {
        const short* Qg = Q + ((size_t)bh * 2048 + (size_t)qt * 64) * 64;
        #pragma unroll
        for (int qs = 0; qs < 4; qs++)
            #pragma unroll
            for (int ks = 0; ks < 2; ks++)
                qf[qs][ks] = *(const bf16x8*)(Qg + (qs*16 + lcol) * 64 + ks*32 + quad*8);
    }

    if (tid < 64) lsum[tid] = 0.f;
    // stage tile 0: K + V (512 chunks each, 2 chunks/thread each)
    #pragma unroll
    for (int i = 0; i < 2; i++) {
        int c = tid + i * 256, row = c >> 3, cs = c & 7, gc = cs ^ (row & 7);
        gl_lds16(Kg + row * 64 + gc * 8, Ks[0] + c * 8);
        gl_lds16(Vg + row * 64 + gc * 8, Vs[0] + c * 8);
    }
    __syncthreads();

    f32x4 o[4];                        // o[tn][r] = O[q=w16+quad*4+r][d=tn*16+lcol]
    #pragma unroll
    for (int tn = 0; tn < 4; tn++) o[tn] = (f32x4){0.f, 0.f, 0.f, 0.f};
    float lp[4] = {0.f, 0.f, 0.f, 0.f};

    const int krow = w * 16 + lcol;            // this wave's K strip rows
    const int ksw  = krow & 7;

    for (int kt = 0; kt < 32; kt++) {
        const int p = kt & 1;
        if (kt < 31) {                 // prefetch next K/V tile (drains at barrier#1)
            #pragma unroll
            for (int i = 0; i < 2; i++) {
                int c = tid + i * 256, row = c >> 3, cs = c & 7, gc = cs ^ (row & 7);
                gl_lds16(Kg + (kt + 1) * 4096 + row * 64 + gc * 8, Ks[p ^ 1] + c * 8);
                gl_lds16(Vg + (kt + 1) * 4096 + row * 64 + gc * 8, Vs[p ^ 1] + c * 8);
            }
        }

        // S^T(strip) = K @ Q^T : lane gets P[q=qs*16+lcol][kv=w*16+quad*4+r]
        f32x4 st[4];
        #pragma unroll
        for (int qs = 0; qs < 4; qs++) st[qs] = (f32x4){0.f, 0.f, 0.f, 0.f};
        #pragma unroll
        for (int ks = 0; ks < 2; ks++) {
            bf16x8 kf = *(const bf16x8*)(Ks[p] + krow * 64 + (((ks*4 + quad) ^ ksw) << 3));
            #pragma unroll
            for (int qs = 0; qs < 4; qs++)
                st[qs] = __builtin_amdgcn_mfma_f32_16x16x32_bf16(kf, qf[qs][ks], st[qs], 0, 0, 0);
        }

        // P = exp2(S^T); 4 consecutive kv per lane -> one b64 write per qs
        #pragma unroll
        for (int qs = 0; qs < 4; qs++) {
            float p0 = exp2fast(st[qs][0]), p1 = exp2fast(st[qs][1]);
            float p2 = exp2fast(st[qs][2]), p3 = exp2fast(st[qs][3]);
            lp[qs] += (p0 + p1) + (p2 + p3);
            uint32_t uu[2] = { packbf(p0, p1), packbf(p2, p3) };
            *(uint32_t*)(Ps + (qs*16 + lcol) * 72 + w*16 + quad*4)     = uu[0];
            *(uint32_t*)(Ps + (qs*16 + lcol) * 72 + w*16 + quad*4 + 2) = uu[1];
        }
        __syncthreads();               // barrier 1: P visible + prefetch DMA drained

        // O += P @ V : A = Ps rows (wave's q-strip), B = V^T rows
        #pragma unroll
        for (int ks = 0; ks < 2; ks++) {
            bf16x8 ap = *(const bf16x8*)(Ps + (w*16 + lcol) * 72 + ks * 32 + quad * 8);
            #pragma unroll
            for (int tn = 0; tn < 4; tn++) {
                int row = tn * 16 + lcol;
                bf16x8 bv = *(const bf16x8*)(Vs[p] + row * 64 +
                                             (((ks * 4 + quad) ^ (row & 7)) << 3));
                o[tn] = __builtin_amdgcn_mfma_f32_16x16x32_bf16(ap, bv, o[tn], 0, 0, 0);
            }
        }
        __syncthreads();               // barrier 2: staging swap + Ps reuse guard
    }

    // ---- epilogue: l cross-wave reduction, then normalize + write ----
    #pragma unroll
    for (int qs = 0; qs < 4; qs++) {
        float v = lp[qs];
        v += __shfl_xor(v, 16, 64);
        v += __shfl_xor(v, 32, 64);
        if (quad == 0) atomicAdd(&lsum[qs*16 + lcol], v);
    }
    __syncthreads();
    #pragma unroll
    for (int tn = 0; tn < 4; tn++) {
        #pragma unroll
        for (int r = 0; r < 4; r++) {
            int q = qt * 64 + w * 16 + quad * 4 + r;
            int d = h * 64 + tn * 16 + lcol;
            float rl = 1.0f / lsum[w * 16 + quad * 4 + r];
            Ab[((size_t)(b * 2048 + q)) * 768 + d] = f2bf(o[tn][r] * rl);
        }
    }
}

// ---------------------------------------------------------------------------
// out-proj GEMM, 64x96 tiles (512 blocks = 2/CU exact): fp32 out + bias
// ---------------------------------------------------------------------------
__global__ __launch_bounds__(256)
void gemm_out(const short* __restrict__ A, const short* __restrict__ Bt,
              const float* __restrict__ bias, float* __restrict__ Of)
{
    __shared__ short As[64 * 32];      // 256 chunks
    __shared__ short Bs[96 * 32];      // 384 chunks
    const int tid = threadIdx.x, lane = tid & 63, w = tid >> 6;
    const int wm = w >> 1, wn = w & 1, quad = lane >> 4, lcol = lane & 15;
    const int bm = blockIdx.y * 64, bn = blockIdx.x * 96;

    f32x4 acc[2][3];
    #pragma unroll
    for (int i = 0; i < 2; i++)
        #pragma unroll
        for (int j = 0; j < 3; j++) acc[i][j] = (f32x4){0.f, 0.f, 0.f, 0.f};

    for (int kt = 0; kt < 768; kt += 32) {
        {
            int row = tid >> 2, cs = tid & 3;
            gl_lds16(A  + (size_t)(bm + row) * 768 + kt + cs * 8, As + tid * 8);
            gl_lds16(Bt + (size_t)(bn + row) * 768 + kt + cs * 8, Bs + tid * 8);
        }
        if (tid < 128) {
            int c = 256 + tid, row = c >> 2, cs = c & 3;
            gl_lds16(Bt + (size_t)(bn + row) * 768 + kt + cs * 8, Bs + c * 8);
        }
        __syncthreads();
        bf16x8 a[2], b[3];
        #pragma unroll
        for (int tm = 0; tm < 2; tm++)
            a[tm] = *(const bf16x8*)(As + (wm*32 + tm*16 + lcol) * 32 + quad * 8);
        #pragma unroll
        for (int tn = 0; tn < 3; tn++)
            b[tn] = *(const bf16x8*)(Bs + (wn*48 + tn*16 + lcol) * 32 + quad * 8);
        #pragma unroll
        for (int tm = 0; tm < 2; tm++)
            #pragma unroll
            for (int tn = 0; tn < 3; tn++)
                acc[tm][tn] = __builtin_amdgcn_mfma_f32_16x16x32_bf16(a[tm], b[tn], acc[tm][tn], 0, 0, 0);
        __syncthreads();
    }
    #pragma unroll
    for (int tm = 0; tm < 2; tm++) {
        #pragma unroll
        for (int tn = 0; tn < 3; tn++) {
            int col = bn + wn*48 + tn*16 + lcol;
            float bv = bias[col];
            #pragma unroll
            for (int reg = 0; reg < 4; reg++) {
                int row = bm + wm*32 + tm*16 + quad*4 + reg;
                Of[(size_t)row * 768 + col] = acc[tm][tn][reg] + bv;
            }
        }
    }
}

// ---------------------------------------------------------------------------
extern "C" void kernel_launch(void* const* d_in, const int* in_sizes, int n_in,
                              void* d_out, int out_size, void* d_ws, size_t ws_size,
                              hipStream_t stream)
{
    (void)in_sizes; (void)n_in; (void)out_size;
    const float* x     = (const float*)d_in[0];
    const float* w_qkv = (const float*)d_in[1];
    const float* b_qkv = (const float*)d_in[2];
    const float* w_out = (const float*)d_in[3];
    const float* b_out = (const float*)d_in[4];
    float* out = (float*)d_out;

    const size_t XSZ = (size_t)4096 * 768;
    const size_t WQ  = (size_t)2304 * 768;
    const size_t WO  = (size_t)768 * 768;
    const size_t HSZ = (size_t)24 * 2048 * 64;
    short* Xb  = (short*)d_ws;
    short* Wqt = Xb + XSZ;
    short* Qb  = Wqt + WQ;
    short* Kb  = Qb + HSZ;
    short* Vt  = Kb + HSZ;
    short* Ab  = Xb;                       // x dead after gemm_qkv

    const bool sepWot = ws_size >= (XSZ + WQ + 3*HSZ + WO) * sizeof(short);
    short* Wot = sepWot ? (Vt + HSZ) : Wqt;   // else alias (w_qkv^T dead after gemm0)

    if (sepWot) {
        prep_k<<<2112, 256, 0, stream>>>(x, Xb, w_qkv, Wqt, w_out, Wot);
        gemm_qkv<<<dim3(24, 32), 256, 0, stream>>>(Xb, Wqt, b_qkv, Qb, Kb, Vt);
    } else {
        prep_k<<<1968, 256, 0, stream>>>(x, Xb, w_qkv, Wqt, w_out, Wot);
        gemm_qkv<<<dim3(24, 32), 256, 0, stream>>>(Xb, Wqt, b_qkv, Qb, Kb, Vt);
        tr_w<<<dim3(12, 12), 256, 0, stream>>>(w_out, Wot, 768, 768);
    }
    attn_k<<<768, 256, 0, stream>>>(Qb, Kb, Vt, Ab);
    gemm_out<<<dim3(8, 64), 256, 0, stream>>>(Ab, Wot, b_out, out);
}